// Round 1
// baseline (1827.349 us; speedup 1.0000x reference)
//
#include <hip/hip_runtime.h>
#include <math.h>

#define EPSV 1e-5f

namespace {
constexpr int NB    = 8;      // batch
constexpr int C     = 512;    // channels
constexpr int NPIX  = 9216;   // H*W
constexpr int K     = 32;     // codewords
constexpr int NCLS  = 19;
constexpr int PB    = 32;     // pixels per tile
constexpr int NTILES= 9;      // tiles per block (32 groups/batch * 9 * 32 = 9216)

// workspace layout (float offsets)
constexpr size_t WS_WT    = 0;                       // 512*512 transposed conv_w
constexpr size_t WS_A2    = 262144;                  // 512 bn2 scale
constexpr size_t WS_B2    = 262656;                  // 512 bn2 bias
constexpr size_t WS_EW    = 263168;                  // 8*32*512
constexpr size_t WS_ACNT  = WS_EW + (size_t)NB*K*C;  // 394240 (8*32)
constexpr size_t WS_EN    = WS_ACNT + NB*K;          // 394496 (8*512)
constexpr size_t WS_GAMMA = WS_EN + (size_t)NB*C;    // 398592 (8*512)

constexpr int HS_STRIDE = 36;    // h tile row stride (pad: bank-rotate + 16B align)
constexpr int WT_STRIDE = 520;   // w tile row stride
constexpr int LDS_FLOATS = C*HS_STRIDE + 32*WT_STRIDE + 32*36 + 32*36 + 32 + 32;
constexpr int LDS_BYTES  = LDS_FLOATS * 4;   // 149,760 < 160 KiB
}

// ---------------- setup kernels ----------------
__global__ __launch_bounds__(256) void k_prep(const float* __restrict__ convw,
                                              float* __restrict__ wT) {
    int idx = blockIdx.x * 256 + threadIdx.x;        // 0..262143
    int o = idx >> 9, c = idx & 511;
    wT[(size_t)c * 512 + o] = convw[(size_t)o * 512 + c];
}

__global__ __launch_bounds__(256) void k_affine(const float* __restrict__ w,
                                                const float* __restrict__ bb,
                                                const float* __restrict__ m,
                                                const float* __restrict__ v,
                                                float* __restrict__ pa,
                                                float* __restrict__ pb) {
    int o = blockIdx.x * 256 + threadIdx.x;
    if (o < C) {
        float s = w[o] * rsqrtf(v[o] + EPSV);
        pa[o] = s;
        pb[o] = bb[o] - m[o] * s;
    }
}

// ---------------- fused conv+bn+relu+encoding ----------------
__global__ __launch_bounds__(256) void k_fused(
    const float* __restrict__ x, const float* __restrict__ wT,
    const float* __restrict__ pA2, const float* __restrict__ pB2,
    const float* __restrict__ cw, const float* __restrict__ scale,
    float* __restrict__ Ew, float* __restrict__ Acnt)
{
    extern __shared__ float smem[];
    float* hs   = smem;                         // [512][36]
    float* wt   = hs  + C * HS_STRIDE;          // [32][520]
    float* xt   = wt  + 32 * WT_STRIDE;         // [32][36]
    float* At   = xt  + 32 * 36;                // [32][36]  (sl then A, [p][k])
    float* x2s  = At  + 32 * 36;                // [32]
    float* acnt = x2s + 32;                     // [32]

    const int t   = threadIdx.x;
    const int bid = blockIdx.x;
    const int b   = bid >> 5;      // batch
    const int g   = bid & 31;      // group within batch

    // phase A mapping: 8x8 thread tile over 512(o) x 32(p)
    const int to = t >> 2;         // o = to*8
    const int tp = t & 3;          // p = tp*8
    // phase B mapping
    const int kb  = t >> 3;        // 0..31
    const int pb4 = (t & 7) * 4;
    // phase C mapping
    const int kg = t >> 5;         // k = kg*4
    const int cg = t & 31;         // c = cg + 32*i

    float Ereg[4][16];
#pragma unroll
    for (int a = 0; a < 4; ++a)
#pragma unroll
        for (int i = 0; i < 16; ++i) Ereg[a][i] = 0.f;

    if (t < 32) acnt[t] = 0.f;

    for (int tile = 0; tile < NTILES; ++tile) {
        const int n0 = g * (PB * NTILES) + tile * PB;
        if (t < 32) x2s[t] = 0.f;

        // ---- phase A: GEMM h = W @ x_tile ----
        float acc[8][8];
#pragma unroll
        for (int i = 0; i < 8; ++i)
#pragma unroll
            for (int j = 0; j < 8; ++j) acc[i][j] = 0.f;

        for (int c0 = 0; c0 < C; c0 += 32) {
            __syncthreads();   // protects xt/wt reuse + prev-tile phase C
            {   // load x tile: 32 rows x 32 px
                const int i = t >> 3;
                const int j = (t & 7) << 2;
                float4 v = *(const float4*)(x + ((size_t)b * C + (c0 + i)) * NPIX + n0 + j);
                *(float4*)(xt + i * 36 + j) = v;
            }
            {   // load w tile transposed from wT: [cc][o]
                const int cc = t >> 3;
                const int ob = (t & 7) << 2;
                const float* src = wT + (size_t)(c0 + cc) * 512 + ob;
                float* dst = wt + cc * WT_STRIDE + ob;
#pragma unroll
                for (int m = 0; m < 16; ++m)
                    *(float4*)(dst + m * 32) = *(const float4*)(src + m * 32);
            }
            __syncthreads();
#pragma unroll 4
            for (int cc = 0; cc < 32; ++cc) {
                const float4 a0 = *(const float4*)(wt + cc * WT_STRIDE + to * 8);
                const float4 a1 = *(const float4*)(wt + cc * WT_STRIDE + to * 8 + 4);
                const float4 b0 = *(const float4*)(xt + cc * 36 + tp * 8);
                const float4 b1 = *(const float4*)(xt + cc * 36 + tp * 8 + 4);
                const float av[8] = {a0.x, a0.y, a0.z, a0.w, a1.x, a1.y, a1.z, a1.w};
                const float bv[8] = {b0.x, b0.y, b0.z, b0.w, b1.x, b1.y, b1.z, b1.w};
#pragma unroll
                for (int i = 0; i < 8; ++i)
#pragma unroll
                    for (int j = 0; j < 8; ++j)
                        acc[i][j] = fmaf(av[i], bv[j], acc[i][j]);
            }
        }
        // epilogue: BN + ReLU -> hs, accumulate x2
        {
            const int o0 = to * 8;
            const float4 s0 = *(const float4*)(pA2 + o0);
            const float4 s1 = *(const float4*)(pA2 + o0 + 4);
            const float4 u0 = *(const float4*)(pB2 + o0);
            const float4 u1 = *(const float4*)(pB2 + o0 + 4);
            const float sa[8] = {s0.x, s0.y, s0.z, s0.w, s1.x, s1.y, s1.z, s1.w};
            const float tb[8] = {u0.x, u0.y, u0.z, u0.w, u1.x, u1.y, u1.z, u1.w};
            float px2[8] = {0, 0, 0, 0, 0, 0, 0, 0};
#pragma unroll
            for (int i = 0; i < 8; ++i) {
#pragma unroll
                for (int j = 0; j < 8; ++j) {
                    float h = fmaf(acc[i][j], sa[i], tb[i]);
                    h = fmaxf(h, 0.f);
                    hs[(o0 + i) * HS_STRIDE + tp * 8 + j] = h;
                    px2[j] = fmaf(h, h, px2[j]);
                }
            }
#pragma unroll
            for (int j = 0; j < 8; ++j) atomicAdd(&x2s[tp * 8 + j], px2[j]);
        }
        __syncthreads();

        // ---- phase B: xc + c2 -> sl stored to At[p][k] ----
        {
            float xc0 = 0, xc1 = 0, xc2 = 0, xc3 = 0, c2 = 0;
            const float* cwr = cw + (size_t)kb * C;
            for (int c4 = 0; c4 < C; c4 += 4) {
                const float4 w4 = *(const float4*)(cwr + c4);
                const float4 h0 = *(const float4*)(hs + (c4 + 0) * HS_STRIDE + pb4);
                const float4 h1 = *(const float4*)(hs + (c4 + 1) * HS_STRIDE + pb4);
                const float4 h2 = *(const float4*)(hs + (c4 + 2) * HS_STRIDE + pb4);
                const float4 h3 = *(const float4*)(hs + (c4 + 3) * HS_STRIDE + pb4);
                xc0 += w4.x * h0.x + w4.y * h1.x + w4.z * h2.x + w4.w * h3.x;
                xc1 += w4.x * h0.y + w4.y * h1.y + w4.z * h2.y + w4.w * h3.y;
                xc2 += w4.x * h0.z + w4.y * h1.z + w4.z * h2.z + w4.w * h3.z;
                xc3 += w4.x * h0.w + w4.y * h1.w + w4.z * h2.w + w4.w * h3.w;
                c2  += w4.x * w4.x + w4.y * w4.y + w4.z * w4.z + w4.w * w4.w;
            }
            const float sc = scale[kb];
            At[(pb4 + 0) * 36 + kb] = sc * (x2s[pb4 + 0] - 2.f * xc0 + c2);
            At[(pb4 + 1) * 36 + kb] = sc * (x2s[pb4 + 1] - 2.f * xc1 + c2);
            At[(pb4 + 2) * 36 + kb] = sc * (x2s[pb4 + 2] - 2.f * xc2 + c2);
            At[(pb4 + 3) * 36 + kb] = sc * (x2s[pb4 + 3] - 2.f * xc3 + c2);
        }
        __syncthreads();

        // ---- softmax over k per pixel (8 lanes x 4 k each) ----
        {
            const int p = t >> 3, j = t & 7;
            float4 v = *(const float4*)(At + p * 36 + j * 4);
            float mx = fmaxf(fmaxf(v.x, v.y), fmaxf(v.z, v.w));
            mx = fmaxf(mx, __shfl_xor(mx, 1));
            mx = fmaxf(mx, __shfl_xor(mx, 2));
            mx = fmaxf(mx, __shfl_xor(mx, 4));
            v.x = expf(v.x - mx); v.y = expf(v.y - mx);
            v.z = expf(v.z - mx); v.w = expf(v.w - mx);
            float s = v.x + v.y + v.z + v.w;
            s += __shfl_xor(s, 1);
            s += __shfl_xor(s, 2);
            s += __shfl_xor(s, 4);
            const float inv = 1.f / s;
            v.x *= inv; v.y *= inv; v.z *= inv; v.w *= inv;
            *(float4*)(At + p * 36 + j * 4) = v;
            atomicAdd(&acnt[j * 4 + 0], v.x);
            atomicAdd(&acnt[j * 4 + 1], v.y);
            atomicAdd(&acnt[j * 4 + 2], v.z);
            atomicAdd(&acnt[j * 4 + 3], v.w);
        }
        __syncthreads();

        // ---- phase C: Ereg[k][c-slice] += A^T @ h ----
        {
#pragma unroll
            for (int p4 = 0; p4 < 8; ++p4) {
                const float4 a0 = *(const float4*)(At + (p4 * 4 + 0) * 36 + kg * 4);
                const float4 a1 = *(const float4*)(At + (p4 * 4 + 1) * 36 + kg * 4);
                const float4 a2 = *(const float4*)(At + (p4 * 4 + 2) * 36 + kg * 4);
                const float4 a3 = *(const float4*)(At + (p4 * 4 + 3) * 36 + kg * 4);
#pragma unroll
                for (int i = 0; i < 16; ++i) {
                    const float4 hv = *(const float4*)(hs + (cg + 32 * i) * HS_STRIDE + p4 * 4);
                    Ereg[0][i] += a0.x * hv.x + a1.x * hv.y + a2.x * hv.z + a3.x * hv.w;
                    Ereg[1][i] += a0.y * hv.x + a1.y * hv.y + a2.y * hv.z + a3.y * hv.w;
                    Ereg[2][i] += a0.z * hv.x + a1.z * hv.y + a2.z * hv.z + a3.z * hv.w;
                    Ereg[3][i] += a0.w * hv.x + a1.w * hv.y + a2.w * hv.z + a3.w * hv.w;
                }
            }
        }
        // next tile's first __syncthreads protects hs/At reuse
    }

    // flush E partials and A counts
#pragma unroll
    for (int a = 0; a < 4; ++a)
#pragma unroll
        for (int i = 0; i < 16; ++i)
            atomicAdd(&Ew[((size_t)(b * K) + kg * 4 + a) * C + cg + 32 * i], Ereg[a][i]);
    if (t < 32) atomicAdd(&Acnt[b * K + t], acnt[t]);
}

// ---------------- E -> bn1 -> relu -> mean_k -> en ----------------
__global__ __launch_bounds__(128) void k_en(
    const float* __restrict__ Ew, const float* __restrict__ Acnt,
    const float* __restrict__ cw,
    const float* __restrict__ bn1w, const float* __restrict__ bn1b,
    const float* __restrict__ bn1m, const float* __restrict__ bn1v,
    float* __restrict__ en)
{
    __shared__ float s1[K], t1[K], ac[K];
    const int b = blockIdx.x >> 2;
    const int c = (blockIdx.x & 3) * 128 + threadIdx.x;
    if (threadIdx.x < K) {
        const int k = threadIdx.x;
        float s = bn1w[k] * rsqrtf(bn1v[k] + EPSV);
        s1[k] = s;
        t1[k] = bn1b[k] - bn1m[k] * s;
        ac[k] = Acnt[b * K + k];
    }
    __syncthreads();
    float s = 0.f;
    for (int k = 0; k < K; ++k) {
        float e = Ew[((size_t)(b * K) + k) * C + c] - ac[k] * cw[(size_t)k * C + c];
        e = fmaf(e, s1[k], t1[k]);
        s += fmaxf(e, 0.f);
    }
    en[(size_t)b * C + c] = s * (1.f / 32.f);
}

// ---------------- gamma = sigmoid(en @ fc^T + b), se = en @ se_w^T + b ----------------
__global__ __launch_bounds__(512) void k_gate(
    const float* __restrict__ en, const float* __restrict__ fcw,
    const float* __restrict__ fcb, const float* __restrict__ sew,
    const float* __restrict__ seb, float* __restrict__ gamma,
    float* __restrict__ se_out)
{
    __shared__ float es[C];
    const int b = blockIdx.x;
    es[threadIdx.x] = en[(size_t)b * C + threadIdx.x];
    __syncthreads();
    {
        const int c = threadIdx.x;
        float z = fcb[c];
        const float* wr = fcw + (size_t)c * C;
        for (int i = 0; i < C; i += 4) {
            const float4 w = *(const float4*)(wr + i);
            z += w.x * es[i] + w.y * es[i + 1] + w.z * es[i + 2] + w.w * es[i + 3];
        }
        gamma[(size_t)b * C + c] = 1.f / (1.f + expf(-z));
    }
    if (threadIdx.x < NCLS * 8) {
        const int j = threadIdx.x >> 3, lane = threadIdx.x & 7;
        float p = 0.f;
        const float* swr = sew + (size_t)j * C;
        for (int i = lane * 64; i < lane * 64 + 64; i += 4) {
            const float4 w = *(const float4*)(swr + i);
            p += w.x * es[i] + w.y * es[i + 1] + w.z * es[i + 2] + w.w * es[i + 3];
        }
        p += __shfl_xor(p, 1);
        p += __shfl_xor(p, 2);
        p += __shfl_xor(p, 4);
        if (lane == 0) se_out[b * NCLS + j] = p + seb[j];
    }
}

// ---------------- out = relu(x * (1 + gamma)) ----------------
__global__ __launch_bounds__(256) void k_out(
    const float* __restrict__ x, const float* __restrict__ gamma,
    float* __restrict__ out)
{
    const int total4 = NB * C * NPIX / 4;
    for (int i = blockIdx.x * blockDim.x + threadIdx.x; i < total4;
         i += gridDim.x * blockDim.x) {
        const int flat = i * 4;
        const int bc = flat / NPIX;
        const float gsc = 1.f + gamma[bc];
        float4 v = *(const float4*)(x + flat);
        v.x = fmaxf(v.x * gsc, 0.f);
        v.y = fmaxf(v.y * gsc, 0.f);
        v.z = fmaxf(v.z * gsc, 0.f);
        v.w = fmaxf(v.w * gsc, 0.f);
        *(float4*)(out + flat) = v;
    }
}

extern "C" void kernel_launch(void* const* d_in, const int* in_sizes, int n_in,
                              void* d_out, int out_size, void* d_ws, size_t ws_size,
                              hipStream_t stream)
{
    const float* x     = (const float*)d_in[0];
    const float* convw = (const float*)d_in[1];
    const float* bn2w  = (const float*)d_in[2];
    const float* bn2b  = (const float*)d_in[3];
    const float* bn2m  = (const float*)d_in[4];
    const float* bn2v  = (const float*)d_in[5];
    const float* cw    = (const float*)d_in[6];
    const float* scale = (const float*)d_in[7];
    const float* bn1w  = (const float*)d_in[8];
    const float* bn1b  = (const float*)d_in[9];
    const float* bn1m  = (const float*)d_in[10];
    const float* bn1v  = (const float*)d_in[11];
    const float* fcw   = (const float*)d_in[12];
    const float* fcb   = (const float*)d_in[13];
    const float* sew   = (const float*)d_in[14];
    const float* seb   = (const float*)d_in[15];

    float* ws = (float*)d_ws;
    float* out = (float*)d_out;
    float* se_out = out + (size_t)NB * C * NPIX;

    // opt-in for >64KB dynamic LDS (ignore result; ROCm may not require it)
    (void)hipFuncSetAttribute((const void*)k_fused,
                              hipFuncAttributeMaxDynamicSharedMemorySize, LDS_BYTES);

    // zero E / Acnt accumulators (must happen every call; ws is poisoned)
    hipMemsetAsync(ws + WS_EW, 0, (size_t)(NB * K * C + NB * K) * sizeof(float), stream);

    k_prep<<<1024, 256, 0, stream>>>(convw, ws + WS_WT);
    k_affine<<<2, 256, 0, stream>>>(bn2w, bn2b, bn2m, bn2v, ws + WS_A2, ws + WS_B2);
    k_fused<<<256, 256, LDS_BYTES, stream>>>(x, ws + WS_WT, ws + WS_A2, ws + WS_B2,
                                             cw, scale, ws + WS_EW, ws + WS_ACNT);
    k_en<<<32, 128, 0, stream>>>(ws + WS_EW, ws + WS_ACNT, cw,
                                 bn1w, bn1b, bn1m, bn1v, ws + WS_EN);
    k_gate<<<8, 512, 0, stream>>>(ws + WS_EN, fcw, fcb, sew, seb,
                                  ws + WS_GAMMA, se_out);
    k_out<<<2048, 256, 0, stream>>>(x, ws + WS_GAMMA, out);
}

// Round 2
// 495.553 us; speedup vs baseline: 3.6875x; 3.6875x over previous
//
#include <hip/hip_runtime.h>
#include <math.h>

#define EPSV 1e-5f

typedef __attribute__((ext_vector_type(8))) short short8;
typedef __attribute__((ext_vector_type(4))) float f32x4;

namespace {
constexpr int NB=8, C=512, NPIX=9216, K=32, NCLS=19;
constexpr int NTOT = NB*NPIX;  // 73728

// ws float offsets
constexpr size_t WS_WB    = 0;          // 512*512 bf16 (131072 float slots)
constexpr size_t WS_A2    = 131072;     // 512
constexpr size_t WS_B2    = 131584;     // 512
constexpr size_t WS_C2    = 132096;     // 32
constexpr size_t WS_X2    = 132128;     // 73728
constexpr size_t WS_EW    = 205856;     // 8*32*512
constexpr size_t WS_ACNT  = 336928;     // 256
constexpr size_t WS_EN    = 337184;     // 4096
constexpr size_t WS_GAMMA = 341280;     // 4096
constexpr size_t WS_XT    = 345376;     // 73728*512 bf16 (18874368 float slots) — xT then hT (in-place)

constexpr int CONV_LDS = (512*64 + 64*64)*2 + 64*4;  // 73984 B
}

__device__ __forceinline__ ushort f2bf(float f){
  unsigned u = __float_as_uint(f);
  return (ushort)((u + 0x7FFFu + ((u>>16)&1u)) >> 16);
}
__device__ __forceinline__ float bf2f(ushort h){
  return __uint_as_float(((unsigned)h)<<16);
}

// ---------------- prep: W -> bf16 ----------------
__global__ __launch_bounds__(256) void k_wcvt(const float* __restrict__ w,
                                              ushort* __restrict__ wb){
  int i = (blockIdx.x*256 + threadIdx.x)*8;
  float4 a = *(const float4*)(w+i), b = *(const float4*)(w+i+4);
  uint4 o;
  o.x = f2bf(a.x) | ((unsigned)f2bf(a.y)<<16);
  o.y = f2bf(a.z) | ((unsigned)f2bf(a.w)<<16);
  o.z = f2bf(b.x) | ((unsigned)f2bf(b.y)<<16);
  o.w = f2bf(b.z) | ((unsigned)f2bf(b.w)<<16);
  *(uint4*)(wb+i) = o;
}

// ---------------- prep: bn2 affine ----------------
__global__ __launch_bounds__(256) void k_affine(const float* __restrict__ w,
                                                const float* __restrict__ bb,
                                                const float* __restrict__ m,
                                                const float* __restrict__ v,
                                                float* __restrict__ pa,
                                                float* __restrict__ pb) {
    int o = blockIdx.x * 256 + threadIdx.x;
    if (o < C) {
        float s = w[o] * rsqrtf(v[o] + EPSV);
        pa[o] = s;
        pb[o] = bb[o] - m[o] * s;
    }
}

// ---------------- prep: c2[k] = sum_c cw^2 ----------------
__global__ __launch_bounds__(256) void k_c2(const float* __restrict__ cw,
                                            float* __restrict__ c2g){
  int t = threadIdx.x;
  int kk = t>>3, part = t&7;
  float s = 0.f;
  for (int c = part*64; c < part*64 + 64; c += 4){
    float4 w = *(const float4*)(cw + kk*512 + c);
    s += w.x*w.x + w.y*w.y + w.z*w.z + w.w*w.w;
  }
  s += __shfl_xor(s, 1);
  s += __shfl_xor(s, 2);
  s += __shfl_xor(s, 4);
  if (part == 0) c2g[kk] = s;
}

// ---------------- transpose+cvt: x[b][c][n] -> xT[n_flat][c] bf16 ----------------
__global__ __launch_bounds__(256) void k_T(const float* __restrict__ x,
                                           ushort* __restrict__ xT){
  __shared__ float xs[64*68];
  const int bid = blockIdx.x;
  const int ct = bid & 7;        // c tile (8)
  const int nt = bid >> 3;       // 0..1151
  const int b = nt / 144, ntl = nt % 144;
  const int c0 = ct*64, n0 = ntl*64;
  const int t = threadIdx.x;
  const float* src = x + ((size_t)b*C + c0)*NPIX + n0;
#pragma unroll
  for (int p = 0; p < 4; ++p){
    const int cr = p*16 + (t>>4);
    const int nc = (t&15)*4;
    *(float4*)(xs + cr*68 + nc) = *(const float4*)(src + (size_t)cr*NPIX + nc);
  }
  __syncthreads();
  const int nr = t>>2, ck = (t&3)*16;
  uint pk[8];
#pragma unroll
  for (int j = 0; j < 8; ++j){
    float f0 = xs[(ck + 2*j  )*68 + nr];
    float f1 = xs[(ck + 2*j+1)*68 + nr];
    pk[j] = (uint)f2bf(f0) | ((uint)f2bf(f1)<<16);
  }
  ushort* dst = xT + ((size_t)(b*NPIX + n0 + nr))*512 + c0 + ck;
  *(uint4*)(dst)   = make_uint4(pk[0],pk[1],pk[2],pk[3]);
  *(uint4*)(dst+8) = make_uint4(pk[4],pk[5],pk[6],pk[7]);
}

// ---------------- conv GEMM (bf16 MFMA) + BN + ReLU -> hT (in-place over xT) + x2 ----------------
// BM=512 (all o), BN=64, BK=64; 4 waves, wave owns 128o x 64n (8x4 frags of 16x16)
__global__ __launch_bounds__(256,2) void k_conv(
  const ushort* __restrict__ Wb, ushort* __restrict__ xT,
  const float* __restrict__ pA2, const float* __restrict__ pB2,
  float* __restrict__ x2g)
{
  extern __shared__ char smem[];
  ushort* As  = (ushort*)smem;            // [512][64] XOR-swizzled
  ushort* Bs  = As + 512*64;              // [64][64] XOR-swizzled
  float*  x2s = (float*)(Bs + 64*64);     // [64]
  const int t = threadIdx.x;
  const int n0 = blockIdx.x * 64;
  const int wave = t>>6, lane = t&63;
  const int lg = lane>>4, l15 = lane&15;

  if (t < 64) x2s[t] = 0.f;

  f32x4 acc[8][4];
#pragma unroll
  for (int mi = 0; mi < 8; ++mi)
#pragma unroll
    for (int nj = 0; nj < 4; ++nj) acc[mi][nj] = (f32x4){0.f,0.f,0.f,0.f};

  const int srow = t>>3, sq = t&7;
  for (int s = 0; s < 8; ++s) {
    const int c0 = s*64;
    __syncthreads();
#pragma unroll
    for (int p = 0; p < 16; ++p) {        // stage A (Wb slice 512x64)
      const int r = p*32 + srow;
      uint4 v = *(const uint4*)(Wb + r*512 + c0 + sq*8);
      *(uint4*)(As + r*64 + (((sq ^ (r&7))&7)<<3)) = v;
    }
#pragma unroll
    for (int p = 0; p < 2; ++p) {         // stage B (xT slice 64x64)
      const int r = p*32 + srow;
      uint4 v = *(const uint4*)(xT + (size_t)(n0+r)*512 + c0 + sq*8);
      *(uint4*)(Bs + r*64 + (((sq ^ (r&7))&7)<<3)) = v;
    }
    __syncthreads();
#pragma unroll
    for (int kk = 0; kk < 2; ++kk) {
      short8 af[8], bfv[4];
#pragma unroll
      for (int mi = 0; mi < 8; ++mi) {
        const int r = wave*128 + mi*16 + l15;
        af[mi] = *(const short8*)(As + r*64 + ((((kk*4+lg) ^ (r&7))&7)<<3));
      }
#pragma unroll
      for (int nj = 0; nj < 4; ++nj) {
        const int r = nj*16 + l15;
        bfv[nj] = *(const short8*)(Bs + r*64 + ((((kk*4+lg) ^ (r&7))&7)<<3));
      }
#pragma unroll
      for (int mi = 0; mi < 8; ++mi)
#pragma unroll
        for (int nj = 0; nj < 4; ++nj)
          acc[mi][nj] = __builtin_amdgcn_mfma_f32_16x16x32_bf16(af[mi], bfv[nj], acc[mi][nj], 0,0,0);
    }
  }

  // epilogue: BN+ReLU, write hT[n][o] bf16 (over xT rows this block owns), x2 accum
  float x2p[4] = {0.f,0.f,0.f,0.f};
#pragma unroll
  for (int mi = 0; mi < 8; ++mi) {
    const int ob = wave*128 + mi*16 + lg*4;
    const float4 sa = *(const float4*)(pA2 + ob);
    const float4 sb = *(const float4*)(pB2 + ob);
#pragma unroll
    for (int nj = 0; nj < 4; ++nj) {
      const int n = n0 + nj*16 + l15;
      f32x4 a = acc[mi][nj];
      float h0 = fmaxf(fmaf(a[0], sa.x, sb.x), 0.f);
      float h1 = fmaxf(fmaf(a[1], sa.y, sb.y), 0.f);
      float h2 = fmaxf(fmaf(a[2], sa.z, sb.z), 0.f);
      float h3 = fmaxf(fmaf(a[3], sa.w, sb.w), 0.f);
      x2p[nj] += h0*h0 + h1*h1 + h2*h2 + h3*h3;
      uint2 pk;
      pk.x = f2bf(h0) | ((unsigned)f2bf(h1)<<16);
      pk.y = f2bf(h2) | ((unsigned)f2bf(h3)<<16);
      *(uint2*)(xT + (size_t)n*512 + ob) = pk;
    }
  }
#pragma unroll
  for (int nj = 0; nj < 4; ++nj) {
    float v = x2p[nj];
    v += __shfl_xor(v, 16);
    v += __shfl_xor(v, 32);
    if (lg == 0) atomicAdd(&x2s[nj*16 + l15], v);
  }
  __syncthreads();
  if (t < 64) x2g[n0 + t] = x2s[t];
}

// ---------------- encoding: xc + softmax + E accumulation (VALU) ----------------
// 768 blocks = 8 batches x 96 groups; each block: 3 tiles of 32 pixels
__global__ __launch_bounds__(256) void k_enc(
  const ushort* __restrict__ hT, const float* __restrict__ x2g,
  const float* __restrict__ cw, const float* __restrict__ scale,
  const float* __restrict__ c2g, float* __restrict__ Ew, float* __restrict__ Acnt)
{
  __shared__ ushort hs[32*520];
  __shared__ float At[32*36];
  __shared__ float x2s[32];
  __shared__ float acnt[32];
  __shared__ float c2s[32], scs[32];
  const int t = threadIdx.x;
  const int bid = blockIdx.x;
  const int b = bid / 96, grp = bid % 96;
  const int n0 = b*NPIX + grp*96;

  if (t < 32){ acnt[t] = 0.f; c2s[t] = c2g[t]; scs[t] = scale[t]; }

  // phase B map
  const int cchunk = t&3, px4 = (t>>2)&7, kk4 = t>>5;
  // phase C map
  const int ckc = t>>5, cc = t&31;

  float Ereg[4][16];
#pragma unroll
  for (int a2 = 0; a2 < 4; ++a2)
#pragma unroll
    for (int i = 0; i < 16; ++i) Ereg[a2][i] = 0.f;

  for (int tile = 0; tile < 3; ++tile){
    const int nt = n0 + tile*32;
    __syncthreads();
    {   // stage h tile [32][512] bf16
      const int px = t>>3, ch = t&7;
      const ushort* src = hT + (size_t)(nt+px)*512 + ch*64;
      ushort* dst = hs + px*520 + ch*64;
#pragma unroll
      for (int q = 0; q < 8; ++q)
        *(uint4*)(dst + q*8) = *(const uint4*)(src + q*8);
    }
    if (t < 32) x2s[t] = x2g[nt + t];
    __syncthreads();

    // ---- xc: thread = (kk4:4kk, px4:4px, cchunk: c interleave) ----
    {
      float xcp[4][4];
#pragma unroll
      for (int a2 = 0; a2 < 4; ++a2)
#pragma unroll
        for (int pp = 0; pp < 4; ++pp) xcp[a2][pp] = 0.f;
      for (int i = 0; i < 32; ++i){
        const int c = i*16 + cchunk*4;
        float4 w0 = *(const float4*)(cw + (kk4*4+0)*512 + c);
        float4 w1 = *(const float4*)(cw + (kk4*4+1)*512 + c);
        float4 w2 = *(const float4*)(cw + (kk4*4+2)*512 + c);
        float4 w3 = *(const float4*)(cw + (kk4*4+3)*512 + c);
#pragma unroll
        for (int pp = 0; pp < 4; ++pp){
          const int px = px4*4 + pp;
          ushort4 hr = *(const ushort4*)(hs + px*520 + c);
          const float h0 = bf2f(hr.x), h1 = bf2f(hr.y), h2 = bf2f(hr.z), h3 = bf2f(hr.w);
          xcp[0][pp] += w0.x*h0 + w0.y*h1 + w0.z*h2 + w0.w*h3;
          xcp[1][pp] += w1.x*h0 + w1.y*h1 + w1.z*h2 + w1.w*h3;
          xcp[2][pp] += w2.x*h0 + w2.y*h1 + w2.z*h2 + w2.w*h3;
          xcp[3][pp] += w3.x*h0 + w3.y*h1 + w3.z*h2 + w3.w*h3;
        }
      }
#pragma unroll
      for (int a2 = 0; a2 < 4; ++a2)
#pragma unroll
        for (int pp = 0; pp < 4; ++pp){
          float v = xcp[a2][pp];
          v += __shfl_xor(v, 1);
          v += __shfl_xor(v, 2);
          if (cchunk == 0){
            const int px = px4*4 + pp, kkx = kk4*4 + a2;
            At[px*36 + kkx] = scs[kkx]*(x2s[px] - 2.f*v + c2s[kkx]);
          }
        }
    }
    __syncthreads();

    // ---- softmax over k per pixel ----
    {
      const int p = t>>3, j = t&7;
      float4 v = *(float4*)(At + p*36 + j*4);
      float mx = fmaxf(fmaxf(v.x, v.y), fmaxf(v.z, v.w));
      mx = fmaxf(mx, __shfl_xor(mx, 1));
      mx = fmaxf(mx, __shfl_xor(mx, 2));
      mx = fmaxf(mx, __shfl_xor(mx, 4));
      v.x = expf(v.x - mx); v.y = expf(v.y - mx);
      v.z = expf(v.z - mx); v.w = expf(v.w - mx);
      float s = v.x + v.y + v.z + v.w;
      s += __shfl_xor(s, 1);
      s += __shfl_xor(s, 2);
      s += __shfl_xor(s, 4);
      const float inv = 1.f / s;
      v.x *= inv; v.y *= inv; v.z *= inv; v.w *= inv;
      *(float4*)(At + p*36 + j*4) = v;
      atomicAdd(&acnt[j*4 + 0], v.x);
      atomicAdd(&acnt[j*4 + 1], v.y);
      atomicAdd(&acnt[j*4 + 2], v.z);
      atomicAdd(&acnt[j*4 + 3], v.w);
    }
    __syncthreads();

    // ---- E accumulation: thread = (ckc: 4kk, cc: 16 c spread as 4x4) ----
    for (int p = 0; p < 32; ++p){
      const float4 P = *(const float4*)(At + p*36 + ckc*4);
      const float Pa[4] = {P.x, P.y, P.z, P.w};
#pragma unroll
      for (int jj = 0; jj < 4; ++jj){
        ushort4 hr = *(const ushort4*)(hs + p*520 + jj*128 + cc*4);
        const float h0 = bf2f(hr.x), h1 = bf2f(hr.y), h2 = bf2f(hr.z), h3 = bf2f(hr.w);
#pragma unroll
        for (int a2 = 0; a2 < 4; ++a2){
          Ereg[a2][jj*4+0] += Pa[a2]*h0;
          Ereg[a2][jj*4+1] += Pa[a2]*h1;
          Ereg[a2][jj*4+2] += Pa[a2]*h2;
          Ereg[a2][jj*4+3] += Pa[a2]*h3;
        }
      }
    }
  }

  // flush
#pragma unroll
  for (int a2 = 0; a2 < 4; ++a2)
#pragma unroll
    for (int jj = 0; jj < 4; ++jj)
#pragma unroll
      for (int q = 0; q < 4; ++q)
        atomicAdd(&Ew[((size_t)b*K + ckc*4+a2)*C + cc*4 + jj*128 + q], Ereg[a2][jj*4+q]);
  if (t < 32) atomicAdd(&Acnt[b*K + t], acnt[t]);
}

// ---------------- E -> bn1 -> relu -> mean_k -> en ----------------
__global__ __launch_bounds__(128) void k_en(
    const float* __restrict__ Ew, const float* __restrict__ Acnt,
    const float* __restrict__ cw,
    const float* __restrict__ bn1w, const float* __restrict__ bn1b,
    const float* __restrict__ bn1m, const float* __restrict__ bn1v,
    float* __restrict__ en)
{
    __shared__ float s1[K], t1[K], ac[K];
    const int b = blockIdx.x >> 2;
    const int c = (blockIdx.x & 3) * 128 + threadIdx.x;
    if (threadIdx.x < K) {
        const int k = threadIdx.x;
        float s = bn1w[k] * rsqrtf(bn1v[k] + EPSV);
        s1[k] = s;
        t1[k] = bn1b[k] - bn1m[k] * s;
        ac[k] = Acnt[b * K + k];
    }
    __syncthreads();
    float s = 0.f;
    for (int k = 0; k < K; ++k) {
        float e = Ew[((size_t)(b * K) + k) * C + c] - ac[k] * cw[(size_t)k * C + c];
        e = fmaf(e, s1[k], t1[k]);
        s += fmaxf(e, 0.f);
    }
    en[(size_t)b * C + c] = s * (1.f / 32.f);
}

// ---------------- gamma / se ----------------
__global__ __launch_bounds__(512) void k_gate(
    const float* __restrict__ en, const float* __restrict__ fcw,
    const float* __restrict__ fcb, const float* __restrict__ sew,
    const float* __restrict__ seb, float* __restrict__ gamma,
    float* __restrict__ se_out)
{
    __shared__ float es[C];
    const int b = blockIdx.x;
    es[threadIdx.x] = en[(size_t)b * C + threadIdx.x];
    __syncthreads();
    {
        const int c = threadIdx.x;
        float z = fcb[c];
        const float* wr = fcw + (size_t)c * C;
        for (int i = 0; i < C; i += 4) {
            const float4 w = *(const float4*)(wr + i);
            z += w.x * es[i] + w.y * es[i + 1] + w.z * es[i + 2] + w.w * es[i + 3];
        }
        gamma[(size_t)b * C + c] = 1.f / (1.f + expf(-z));
    }
    if (threadIdx.x < NCLS * 8) {
        const int j = threadIdx.x >> 3, lane = threadIdx.x & 7;
        float p = 0.f;
        const float* swr = sew + (size_t)j * C;
        for (int i = lane * 64; i < lane * 64 + 64; i += 4) {
            const float4 w = *(const float4*)(swr + i);
            p += w.x * es[i] + w.y * es[i + 1] + w.z * es[i + 2] + w.w * es[i + 3];
        }
        p += __shfl_xor(p, 1);
        p += __shfl_xor(p, 2);
        p += __shfl_xor(p, 4);
        if (lane == 0) se_out[b * NCLS + j] = p + seb[j];
    }
}

// ---------------- out = relu(x * (1 + gamma)) ----------------
__global__ __launch_bounds__(256) void k_out(
    const float* __restrict__ x, const float* __restrict__ gamma,
    float* __restrict__ out)
{
    const int total4 = NB * C * NPIX / 4;
    for (int i = blockIdx.x * blockDim.x + threadIdx.x; i < total4;
         i += gridDim.x * blockDim.x) {
        const int flat = i * 4;
        const int bc = flat / NPIX;
        const float gsc = 1.f + gamma[bc];
        float4 v = *(const float4*)(x + flat);
        v.x = fmaxf(v.x * gsc, 0.f);
        v.y = fmaxf(v.y * gsc, 0.f);
        v.z = fmaxf(v.z * gsc, 0.f);
        v.w = fmaxf(v.w * gsc, 0.f);
        *(float4*)(out + flat) = v;
    }
}

extern "C" void kernel_launch(void* const* d_in, const int* in_sizes, int n_in,
                              void* d_out, int out_size, void* d_ws, size_t ws_size,
                              hipStream_t stream)
{
    const float* x     = (const float*)d_in[0];
    const float* convw = (const float*)d_in[1];
    const float* bn2w  = (const float*)d_in[2];
    const float* bn2b  = (const float*)d_in[3];
    const float* bn2m  = (const float*)d_in[4];
    const float* bn2v  = (const float*)d_in[5];
    const float* cw    = (const float*)d_in[6];
    const float* scale = (const float*)d_in[7];
    const float* bn1w  = (const float*)d_in[8];
    const float* bn1b  = (const float*)d_in[9];
    const float* bn1m  = (const float*)d_in[10];
    const float* bn1v  = (const float*)d_in[11];
    const float* fcw   = (const float*)d_in[12];
    const float* fcb   = (const float*)d_in[13];
    const float* sew   = (const float*)d_in[14];
    const float* seb   = (const float*)d_in[15];

    float* ws = (float*)d_ws;
    float* out = (float*)d_out;
    float* se_out = out + (size_t)NB * C * NPIX;

    ushort* Wb = (ushort*)(ws + WS_WB);
    ushort* xT = (ushort*)(ws + WS_XT);   // becomes hT after k_conv (in-place)

    (void)hipFuncSetAttribute((const void*)k_conv,
                              hipFuncAttributeMaxDynamicSharedMemorySize, CONV_LDS);

    // zero E / Acnt accumulators (ws is poisoned once; atomics need zeros each call)
    hipMemsetAsync(ws + WS_EW, 0, (size_t)(NB*K*C + NB*K) * sizeof(float), stream);

    k_wcvt<<<128, 256, 0, stream>>>(convw, Wb);
    k_affine<<<2, 256, 0, stream>>>(bn2w, bn2b, bn2m, bn2v, ws + WS_A2, ws + WS_B2);
    k_c2<<<1, 256, 0, stream>>>(cw, ws + WS_C2);
    k_T<<<9216, 256, 0, stream>>>(x, xT);
    k_conv<<<1152, 256, CONV_LDS, stream>>>(Wb, xT, ws + WS_A2, ws + WS_B2, ws + WS_X2);
    k_enc<<<768, 256, 0, stream>>>(xT, ws + WS_X2, cw, scale, ws + WS_C2,
                                   ws + WS_EW, ws + WS_ACNT);
    k_en<<<32, 128, 0, stream>>>(ws + WS_EW, ws + WS_ACNT, cw,
                                 bn1w, bn1b, bn1m, bn1v, ws + WS_EN);
    k_gate<<<8, 512, 0, stream>>>(ws + WS_EN, fcw, fcb, sew, seb,
                                  ws + WS_GAMMA, se_out);
    k_out<<<2048, 256, 0, stream>>>(x, ws + WS_GAMMA, out);
}